// Round 10
// baseline (1322.768 us; speedup 1.0000x reference)
//
#include <hip/hip_runtime.h>
#include <hip/hip_bf16.h>
#include <cstdio>

#define HID 256

using short8  = __attribute__((ext_vector_type(8))) short;
using floatx4 = __attribute__((ext_vector_type(4))) float;
using uintx8  = __attribute__((ext_vector_type(8))) unsigned int;

__device__ inline unsigned short bf16_rn(float x) {
    unsigned u = __float_as_uint(x);
    return (unsigned short)((u + 0x7FFFu + ((u >> 16) & 1u)) >> 16);
}
__device__ inline float bf2f(unsigned short u) {
    return __uint_as_float(((unsigned)u) << 16);
}
// packed uint32 = (hi_bf16 << 16) | lo_bf16
__device__ inline unsigned pack_hl(float v) {
    unsigned short h = bf16_rn(v);
    unsigned short lo = bf16_rn(v - bf2f(h));
    return ((unsigned)h << 16) | (unsigned)lo;
}
__device__ inline float unpack_sum(unsigned u) {
    return __uint_as_float(u & 0xFFFF0000u) + __uint_as_float(u << 16);
}
// uintx8 (8 packed elems) -> hi short8 + lo short8
__device__ inline void unpack8(uintx8 u, short8& h, short8& l) {
    union { unsigned w[4]; short8 s; } H, L;
#pragma unroll
    for (int i = 0; i < 4; i++) {
        unsigned a = u[2 * i], b = u[2 * i + 1];
        H.w[i] = (a >> 16) | (b & 0xFFFF0000u);
        L.w[i] = (a & 0x0000FFFFu) | (b << 16);
    }
    h = H.s; l = L.s;
}

// ---------------- diagnostic marker (ws too small) ----------------
__global__ void marker_k(float* __restrict__ out, int n, float v) {
    int i = blockIdx.x * blockDim.x + threadIdx.x;
    if (i < n) out[i] = v;
}

// ---------------- int64-vs-int32 detection ----------------
__global__ void detect64_k(const unsigned* __restrict__ eiw, int E,
                           const unsigned* __restrict__ bw, int Nh,
                           int* __restrict__ any_nonzero) {
    int total = E + Nh;
    unsigned loc = 0;
    for (int i = blockIdx.x * blockDim.x + threadIdx.x; i < total;
         i += gridDim.x * blockDim.x) {
        loc |= (i < E) ? eiw[2 * i + 1] : bw[2 * (i - E) + 1];
    }
    if (loc) atomicOr(any_nonzero, 1);
}

__global__ void norm_idx_k(const int* __restrict__ src, int* __restrict__ dst,
                           int n, const int* __restrict__ any_nonzero) {
    int is64 = (any_nonzero[0] == 0);
    for (int i = blockIdx.x * blockDim.x + threadIdx.x; i < n;
         i += gridDim.x * blockDim.x) {
        dst[i] = is64 ? src[2 * i] : src[i];
    }
}

// ---------------- graph boundaries (batch is sorted) ----------------
__global__ void pool_bounds_k(const int* __restrict__ batch, int N, int G,
                              int* __restrict__ starts) {
    int g = blockIdx.x * blockDim.x + threadIdx.x;
    if (g > G) return;
    int lo = 0, hi = N;
    while (lo < hi) {
        int mid = (lo + hi) >> 1;
        if (batch[mid] < g) lo = mid + 1; else hi = mid;
    }
    starts[g] = lo;
}

// ---------------- CSR build ----------------
__global__ void deg_count_k(const int* __restrict__ ei, int E, int N,
                            int* __restrict__ deg) {
    int e = blockIdx.x * blockDim.x + threadIdx.x;
    if (e >= E) return;
    int s = ei[e];
    int d = ei[E + e];
    if ((unsigned)s >= (unsigned)N || (unsigned)d >= (unsigned)N) return;
    atomicAdd(&deg[d], 1);
}

#define SCAN_BLK 256

__global__ __launch_bounds__(SCAN_BLK) void scan_a_k(const int* __restrict__ deg,
                                                     int* __restrict__ bsum, int N) {
    __shared__ int red[SCAN_BLK];
    int i = blockIdx.x * SCAN_BLK + threadIdx.x;
    int v = (i < N) ? deg[i] : 0;
    red[threadIdx.x] = v;
    __syncthreads();
#pragma unroll
    for (int off = SCAN_BLK / 2; off > 0; off >>= 1) {
        if (threadIdx.x < off) red[threadIdx.x] += red[threadIdx.x + off];
        __syncthreads();
    }
    if (threadIdx.x == 0) bsum[blockIdx.x] = red[0];
}

__global__ __launch_bounds__(1024) void scan_b_k(int* __restrict__ bsum, int nb) {
    __shared__ int tsum[1024];
    int t = threadIdx.x;
    int v = (t < nb) ? bsum[t] : 0;
    tsum[t] = v;
    __syncthreads();
    for (int off = 1; off < 1024; off <<= 1) {
        int u = (t >= off) ? tsum[t - off] : 0;
        __syncthreads();
        tsum[t] += u;
        __syncthreads();
    }
    if (t < nb) bsum[t] = tsum[t] - v;
}

__global__ __launch_bounds__(SCAN_BLK) void scan_c_k(const int* __restrict__ deg,
                                                     const int* __restrict__ bsum,
                                                     int* __restrict__ row_ptr, int N) {
    __shared__ int tsum[SCAN_BLK];
    int t = threadIdx.x;
    int i = blockIdx.x * SCAN_BLK + t;
    int v = (i < N) ? deg[i] : 0;
    tsum[t] = v;
    __syncthreads();
    for (int off = 1; off < SCAN_BLK; off <<= 1) {
        int u = (t >= off) ? tsum[t - off] : 0;
        __syncthreads();
        tsum[t] += u;
        __syncthreads();
    }
    if (i <= N) row_ptr[i] = tsum[t] - v + bsum[blockIdx.x];
}

__global__ __launch_bounds__(1024) void scan_rowptr_k(const int* __restrict__ deg,
                                                      int* __restrict__ row_ptr, int N) {
    __shared__ int tsum[1024];
    int t = threadIdx.x;
    int chunk = (N + 1023) / 1024;
    int lo = t * chunk;
    int hi = min(lo + chunk, N);
    int s = 0;
    for (int i = lo; i < hi; i++) s += deg[i];
    tsum[t] = s;
    __syncthreads();
    for (int off = 1; off < 1024; off <<= 1) {
        int v = (t >= off) ? tsum[t - off] : 0;
        __syncthreads();
        tsum[t] += v;
        __syncthreads();
    }
    int run = (t == 0) ? 0 : tsum[t - 1];
    for (int i = lo; i < hi; i++) { row_ptr[i] = run; run += deg[i]; }
    if (hi >= N && lo <= N) row_ptr[N] = run;
}

__global__ void fill_csr_k(const int* __restrict__ ei, int E, int N,
                           const int* __restrict__ row_ptr, int* __restrict__ cursor,
                           int* __restrict__ esrc) {
    int e = blockIdx.x * blockDim.x + threadIdx.x;
    if (e >= E) return;
    int s = ei[e];
    int d = ei[E + e];
    if ((unsigned)s >= (unsigned)N || (unsigned)d >= (unsigned)N) return;
    int pos = atomicAdd(&cursor[d], 1);
    esrc[row_ptr[d] + pos] = s;
}

// ---------------- gather aggregation, 28-wide (layer 1, fp32) ----------------
__global__ void gather28_k(const float* __restrict__ x, const int* __restrict__ row_ptr,
                           const int* __restrict__ esrc, float* __restrict__ Q28, int N) {
    int gid = blockIdx.x * blockDim.x + threadIdx.x;
    int node = gid >> 5;
    if (node >= N) return;
    int lane = gid & 31;
    if (lane >= 28) return;
    int s = row_ptr[node], e = row_ptr[node + 1];
    float acc = 0.f;
    for (int i = s; i < e; i++) {
        int src = esrc[i];
        acc += x[(size_t)src * 28 + lane];
    }
    Q28[(size_t)node * 28 + lane] = acc;
}

// ---------------- gather: Pp(packed) -> Qp(packed) ----------------
__global__ void gather256p_k(const unsigned* __restrict__ Pp,
                             const int* __restrict__ row_ptr,
                             const int* __restrict__ esrc,
                             unsigned* __restrict__ Qp, int N) {
    int gid = blockIdx.x * blockDim.x + threadIdx.x;
    int node = gid >> 6;
    if (node >= N) return;
    int lane = gid & 63;
    int s = row_ptr[node], e = row_ptr[node + 1];
    float a0 = 0.f, a1 = 0.f, a2 = 0.f, a3 = 0.f;
    for (int i = s; i < e; i++) {
        int src = esrc[i];
        uint4 u = *(const uint4*)(Pp + (size_t)src * HID + lane * 4);
        a0 += unpack_sum(u.x);
        a1 += unpack_sum(u.y);
        a2 += unpack_sum(u.z);
        a3 += unpack_sum(u.w);
    }
    uint4 o;
    o.x = pack_hl(a0); o.y = pack_hl(a1); o.z = pack_hl(a2); o.w = pack_hl(a3);
    *(uint4*)(Qp + (size_t)node * HID + lane * 4) = o;
}

// ---------------- layer 1 fused -> Pp (packed) ----------------
__global__ __launch_bounds__(256) void l1_fused_k(
    const float* __restrict__ x, const float* __restrict__ agg,
    const float* __restrict__ Wrel, const float* __restrict__ Wroot,
    const float* __restrict__ bias, unsigned* __restrict__ Pp, int M) {
    __shared__ float As[64][28];
    __shared__ float Xs[64][28];
    int t = threadIdx.x;
    int n0 = blockIdx.x * 64;
    float wrel[28], wroot[28];
#pragma unroll
    for (int k = 0; k < 28; k++) {
        wrel[k]  = Wrel[t * 28 + k];
        wroot[k] = Wroot[t * 28 + k];
    }
    float b = bias[t];
    for (int idx = t; idx < 64 * 28; idx += 256) {
        int r = idx / 28;
        int c = idx - r * 28;
        int gr = n0 + r;
        As[r][c] = (gr < M) ? agg[(size_t)gr * 28 + c] : 0.f;
        Xs[r][c] = (gr < M) ? x[(size_t)gr * 28 + c] : 0.f;
    }
    __syncthreads();
    int nmax = min(64, M - n0);
    for (int n = 0; n < nmax; n++) {
        float acc = b;
#pragma unroll
        for (int k4 = 0; k4 < 28; k4 += 4) {
            float4 a  = *(const float4*)&As[n][k4];
            float4 xx = *(const float4*)&Xs[n][k4];
            acc += a.x * wrel[k4] + a.y * wrel[k4 + 1] + a.z * wrel[k4 + 2] + a.w * wrel[k4 + 3];
            acc += xx.x * wroot[k4] + xx.y * wroot[k4 + 1] + xx.z * wroot[k4 + 2] + xx.w * wroot[k4 + 3];
        }
        Pp[(size_t)(n0 + n) * HID + t] = pack_hl(fmaxf(acc, 0.f));
    }
}

// ---------------- weight split: 6 matrices fp32 -> packed uint ----------------
__global__ void wsplit6_k(const float* W0, const float* W1, const float* W2,
                          const float* W3, const float* W4, const float* W5,
                          unsigned* __restrict__ outp, int n) {
    int i = blockIdx.x * blockDim.x + threadIdx.x;
    if (i >= n) return;
    const float* W = (blockIdx.y == 0) ? W0 : (blockIdx.y == 1) ? W1 :
                     (blockIdx.y == 2) ? W2 : (blockIdx.y == 3) ? W3 :
                     (blockIdx.y == 4) ? W4 : W5;
    outp[(size_t)blockIdx.y * n + i] = pack_hl(W[i]);
}

// ---------------- register-fragment MFMA GEMM (no LDS, no staging) ----------------
// Pp[strip] = relu(Qp@Wr.T + Pp@Wo.T + bias). 64-row strip, 4 waves, wave w owns
// cols [w*64, w*64+64). All operands packed uint (hi|lo bf16). Fragments loaded
// directly from global (A reuse via L1/L2; W is 1.5 MB, L2-resident).
__global__ __launch_bounds__(256) void gemm_reg_k(
    const unsigned* __restrict__ Qp, const unsigned* __restrict__ Wr,
    unsigned* __restrict__ Pp, const unsigned* __restrict__ Wo,
    const float* __restrict__ bias, int M) {
    int t = threadIdx.x;
    int w = t >> 6;
    int l = t & 63;
    int brow = blockIdx.x * 64;
    int frow = l & 15;
    int fg   = l >> 4;

    floatx4 acc[4][4];
#pragma unroll
    for (int i = 0; i < 4; i++)
#pragma unroll
        for (int j = 0; j < 4; j++) acc[i][j] = (floatx4){0.f, 0.f, 0.f, 0.f};

    const unsigned* Alist[2] = {Qp, Pp};
    const unsigned* Wlist[2] = {Wr, Wo};

    for (int ph = 0; ph < 2; ph++) {
        const unsigned* A = Alist[ph];
        const unsigned* W = Wlist[ph];
#pragma unroll 2
        for (int c = 0; c < 8; c++) {
            int kb = c * 32 + fg * 8;
            uintx8 au[4], wu[4];
#pragma unroll
            for (int rt = 0; rt < 4; rt++)
                au[rt] = *(const uintx8*)(A + (size_t)(brow + rt * 16 + frow) * HID + kb);
#pragma unroll
            for (int ct = 0; ct < 4; ct++)
                wu[ct] = *(const uintx8*)(W + (size_t)(w * 64 + ct * 16 + frow) * HID + kb);
            short8 ah[4], al[4], wh[4], wl[4];
#pragma unroll
            for (int rt = 0; rt < 4; rt++) unpack8(au[rt], ah[rt], al[rt]);
#pragma unroll
            for (int ct = 0; ct < 4; ct++) unpack8(wu[ct], wh[ct], wl[ct]);
#pragma unroll
            for (int rt = 0; rt < 4; rt++)
#pragma unroll
                for (int ct = 0; ct < 4; ct++) {
                    acc[rt][ct] = __builtin_amdgcn_mfma_f32_16x16x32_bf16(
                        ah[rt], wh[ct], acc[rt][ct], 0, 0, 0);
                    acc[rt][ct] = __builtin_amdgcn_mfma_f32_16x16x32_bf16(
                        al[rt], wh[ct], acc[rt][ct], 0, 0, 0);
                    acc[rt][ct] = __builtin_amdgcn_mfma_f32_16x16x32_bf16(
                        ah[rt], wl[ct], acc[rt][ct], 0, 0, 0);
                }
        }
    }

    // all phase-2 reads of this strip complete before in-place writes
    __syncthreads();

#pragma unroll
    for (int ct = 0; ct < 4; ct++) {
        int gc = w * 64 + ct * 16 + frow;
        float bs = bias[gc];
#pragma unroll
        for (int rt = 0; rt < 4; rt++) {
            floatx4 a = acc[rt][ct];
#pragma unroll
            for (int r = 0; r < 4; r++) {
                int gr = brow + rt * 16 + fg * 4 + r;
                if (gr < M)
                    Pp[(size_t)gr * HID + gc] = pack_hl(fmaxf(a[r] + bs, 0.f));
            }
        }
    }
}

// ---------------- per-layer mean-pool slice (packed input) ----------------
__global__ __launch_bounds__(256) void pool_slice_k(const unsigned* __restrict__ Pp,
                                                    const int* __restrict__ starts,
                                                    float* __restrict__ gslice, int N) {
    int g = blockIdx.x;
    int t = threadIdx.x;
    int s = starts[g], e = starts[g + 1];
    s = max(0, min(s, N));
    e = max(s, min(e, N));
    float a = 0.f;
    for (int n = s; n < e; n++) a += unpack_sum(Pp[(size_t)n * HID + t]);
    float inv = 1.f / (float)max(e - s, 1);
    gslice[(size_t)g * 1024 + t] = a * inv;
}

// ---------------- out-of-place dual GEMM (MLP head, fp32) ----------------
#define BM 64
#define BN 64
#define BK 32
#define LP 68

__global__ __launch_bounds__(256) void gemm_dual_k(
    const float* __restrict__ A1, int lda1, const float* __restrict__ W1,
    const float* __restrict__ A2, int lda2, const float* __restrict__ W2,
    const float* __restrict__ bias, float* __restrict__ out, int ldout,
    int M, int K1, int K2, int relu) {
    __shared__ float As[BK][LP];
    __shared__ float Ws[BK][LP];
    int t = threadIdx.x;
    int brow = blockIdx.x * BM;
    int bcol = blockIdx.y * BN;
    int tx = t & 15, ty = t >> 4;
    float acc[4][4] = {{0.f}};
    int Ktot = K1 + K2;
    int srow = t >> 3;
    int sk4 = (t & 7) << 2;

    for (int kk = 0; kk < Ktot; kk += BK) {
        int phase2 = (kk >= K1);
        const float* A = phase2 ? A2 : A1;
        const float* W = phase2 ? W2 : W1;
        int lda = phase2 ? lda2 : lda1;
        int ldw = phase2 ? K2 : K1;
        int kbase = phase2 ? (kk - K1) : kk;
#pragma unroll
        for (int i = 0; i < 2; i++) {
            int r = srow + i * 32;
            int gr = brow + r;
            float4 v = make_float4(0.f, 0.f, 0.f, 0.f);
            if (gr < M) v = *(const float4*)(A + (size_t)gr * lda + kbase + sk4);
            As[sk4 + 0][r] = v.x; As[sk4 + 1][r] = v.y;
            As[sk4 + 2][r] = v.z; As[sk4 + 3][r] = v.w;
            float4 w = *(const float4*)(W + (size_t)(bcol + r) * ldw + kbase + sk4);
            Ws[sk4 + 0][r] = w.x; Ws[sk4 + 1][r] = w.y;
            Ws[sk4 + 2][r] = w.z; Ws[sk4 + 3][r] = w.w;
        }
        __syncthreads();
#pragma unroll
        for (int k = 0; k < BK; k++) {
            float4 a = *(const float4*)&As[k][ty << 2];
            float4 w = *(const float4*)&Ws[k][tx << 2];
            float av[4] = {a.x, a.y, a.z, a.w};
            float wv[4] = {w.x, w.y, w.z, w.w};
#pragma unroll
            for (int i = 0; i < 4; i++)
#pragma unroll
                for (int j = 0; j < 4; j++)
                    acc[i][j] = fmaf(av[i], wv[j], acc[i][j]);
        }
        __syncthreads();
    }
#pragma unroll
    for (int i = 0; i < 4; i++) {
        int gr = brow + (ty << 2) + i;
        if (gr >= M) continue;
#pragma unroll
        for (int j = 0; j < 4; j++) {
            int gc = bcol + (tx << 2) + j;
            float v = acc[i][j] + bias[gc];
            if (relu) v = fmaxf(v, 0.f);
            out[(size_t)gr * ldout + gc] = v;
        }
    }
}

// ---------------- fc4 ----------------
__global__ void fc4_k(const float* __restrict__ in, const float* __restrict__ w,
                      const float* __restrict__ b, float* __restrict__ out, int M) {
    int gid = blockIdx.x * blockDim.x + threadIdx.x;
    int row = gid >> 6;
    if (row >= M) return;
    int lane = gid & 63;
    float4 v  = *(const float4*)(in + (size_t)row * HID + lane * 4);
    float4 ww = *(const float4*)(w + lane * 4);
    float acc = v.x * ww.x + v.y * ww.y + v.z * ww.z + v.w * ww.w;
#pragma unroll
    for (int off = 32; off; off >>= 1) acc += __shfl_down(acc, off);
    if (lane == 0) out[row] = acc + b[0];
}

extern "C" void kernel_launch(void* const* d_in, const int* in_sizes, int n_in,
                              void* d_out, int out_size, void* d_ws, size_t ws_size,
                              hipStream_t stream) {
    const int N = in_sizes[0] / 28;       // 100000
    const int E = in_sizes[1] / 2;        // 320000
    const int G = out_size;               // 4096

    const float* x        = (const float*)d_in[0];
    const int*   ei_raw   = (const int*)d_in[1];
    const int*   b_raw    = (const int*)d_in[2];
    const float* W1_rel  = (const float*)d_in[3];
    const float* b1      = (const float*)d_in[4];
    const float* W1_root = (const float*)d_in[5];
    const float* W2_rel  = (const float*)d_in[6];
    const float* b2      = (const float*)d_in[7];
    const float* W2_root = (const float*)d_in[8];
    const float* W3_rel  = (const float*)d_in[9];
    const float* b3      = (const float*)d_in[10];
    const float* W3_root = (const float*)d_in[11];
    const float* W4_rel  = (const float*)d_in[12];
    const float* b4      = (const float*)d_in[13];
    const float* W4_root = (const float*)d_in[14];
    const float* fc1_w = (const float*)d_in[15];
    const float* fc1_b = (const float*)d_in[16];
    const float* fc2_w = (const float*)d_in[17];
    const float* fc2_b = (const float*)d_in[18];
    const float* fc3_w = (const float*)d_in[19];
    const float* fc3_b = (const float*)d_in[20];
    const float* fc4_w = (const float*)d_in[21];
    const float* fc4_b = (const float*)d_in[22];
    float* out = (float*)d_out;

    // ---- workspace layout (float/uint units). Pp/Qp = N*HID packed uints ----
    size_t fN  = (size_t)N * HID;
    size_t off_P      = 0;
    size_t off_Q      = off_P + fN;     // fp32 Q28 prefix for layer 1, packed later
    size_t off_gpool  = off_Q + fN;
    size_t off_t1     = off_gpool + (size_t)G * 1024;
    size_t off_t2     = off_t1 + (size_t)G * HID;
    size_t off_ei     = off_t2 + (size_t)G * HID;
    size_t off_batch  = off_ei + (size_t)2 * E;
    size_t off_starts = off_batch + (size_t)N;
    size_t off_flag   = off_starts + (size_t)(G + 1);
    size_t off_deg    = off_flag + 1;
    size_t off_cur    = off_deg + (size_t)N;
    size_t off_rowp   = off_cur + (size_t)N;
    size_t off_bsum   = off_rowp + (size_t)(N + 1);
    size_t off_esrc   = off_bsum + 1024;
    size_t off_wsplit = (off_esrc + (size_t)E + 7) & ~(size_t)7;  // 32B-align
    size_t need = (off_wsplit + 6 * 65536 + 16) * 4;

    if (ws_size < need) {
        fprintf(stderr, "[kernel_launch] ws too small: ws=%zu need=%zu\n", ws_size, need);
        marker_k<<<(G + 255) / 256, 256, 0, stream>>>(out, G, (float)(ws_size >> 20));
        return;
    }

    float* wsf   = (float*)d_ws;
    unsigned* Pp = (unsigned*)(wsf + off_P);
    float* Q     = wsf + off_Q;
    unsigned* Qp = (unsigned*)Q;
    float* gpool = wsf + off_gpool;
    float* t1    = wsf + off_t1;
    float* t2    = wsf + off_t2;
    int* nei     = (int*)(wsf + off_ei);
    int* nbatch  = (int*)(wsf + off_batch);
    int* starts  = (int*)(wsf + off_starts);
    int* flag    = (int*)(wsf + off_flag);
    int* deg     = (int*)(wsf + off_deg);
    int* cursor  = (int*)(wsf + off_cur);
    int* row_ptr = (int*)(wsf + off_rowp);
    int* bsum    = (int*)(wsf + off_bsum);
    int* esrc    = (int*)(wsf + off_esrc);
    unsigned* Wu = (unsigned*)(wsf + off_wsplit);

    // ---- normalize index dtype (int64 vs int32) on-device ----
    hipMemsetAsync(flag, 0, sizeof(int), stream);
    detect64_k<<<1024, 256, 0, stream>>>((const unsigned*)ei_raw, E,
                                         (const unsigned*)b_raw, N / 2, flag);
    norm_idx_k<<<1024, 256, 0, stream>>>(ei_raw, nei, 2 * E, flag);
    norm_idx_k<<<512, 256, 0, stream>>>(b_raw, nbatch, N, flag);

    pool_bounds_k<<<(G + 1 + 255) / 256, 256, 0, stream>>>(nbatch, N, G, starts);

    // ---- build CSR by destination ----
    hipMemsetAsync(deg, 0, 2 * (size_t)N * sizeof(int), stream);
    deg_count_k<<<(E + 255) / 256, 256, 0, stream>>>(nei, E, N, deg);
    int nb = (N + 1 + SCAN_BLK - 1) / SCAN_BLK;
    if (nb <= 1024) {
        scan_a_k<<<nb, SCAN_BLK, 0, stream>>>(deg, bsum, N);
        scan_b_k<<<1, 1024, 0, stream>>>(bsum, nb);
        scan_c_k<<<nb, SCAN_BLK, 0, stream>>>(deg, bsum, row_ptr, N);
    } else {
        scan_rowptr_k<<<1, 1024, 0, stream>>>(deg, row_ptr, N);
    }
    fill_csr_k<<<(E + 255) / 256, 256, 0, stream>>>(nei, E, N, row_ptr, cursor, esrc);

    // ---- pre-split GraphConv weights to packed uint ----
    wsplit6_k<<<dim3((65536 + 255) / 256, 6), 256, 0, stream>>>(
        W2_rel, W2_root, W3_rel, W3_root, W4_rel, W4_root, Wu, 65536);

    // ---- layer 1: gather 28-wide (fp32) into Q, fused GEMM -> Pp (packed) ----
    gather28_k<<<((size_t)N * 32 + 255) / 256, 256, 0, stream>>>(x, row_ptr, esrc, Q, N);
    l1_fused_k<<<(N + 63) / 64, 256, 0, stream>>>(x, Q, W1_rel, W1_root, b1, Pp, N);
    pool_slice_k<<<G, 256, 0, stream>>>(Pp, starts, gpool + 0, N);

    // ---- layers 2..4: gather Pp -> Qp; register-MFMA GEMM in-place on Pp; pool ----
    int nstrips = (N + 63) / 64;
    const float* bb[3] = {b2, b3, b4};
    for (int l = 0; l < 3; l++) {
        gather256p_k<<<((size_t)N * 64 + 255) / 256, 256, 0, stream>>>(Pp, row_ptr, esrc, Qp, N);
        gemm_reg_k<<<nstrips, 256, 0, stream>>>(
            Qp, Wu + (size_t)(2 * l) * 65536,
            Pp, Wu + (size_t)(2 * l + 1) * 65536, bb[l], N);
        pool_slice_k<<<G, 256, 0, stream>>>(Pp, starts, gpool + 256 * (l + 1), N);
    }

    // ---- MLP head ----
    dim3 gdimG(G / BM, HID / BN);
    gemm_dual_k<<<gdimG, 256, 0, stream>>>(gpool, 1024, fc1_w, nullptr, 0, nullptr,
                                           fc1_b, t1, HID, G, 1024, 0, 1);
    gemm_dual_k<<<gdimG, 256, 0, stream>>>(t1, HID, fc2_w, nullptr, 0, nullptr,
                                           fc2_b, t2, HID, G, HID, 0, 1);
    gemm_dual_k<<<gdimG, 256, 0, stream>>>(t2, HID, fc3_w, nullptr, 0, nullptr,
                                           fc3_b, t1, HID, G, HID, 0, 1);
    fc4_k<<<(G * 64 + 255) / 256, 256, 0, stream>>>(t1, fc4_w, fc4_b, out, G);
}

// Round 11
// 1120.753 us; speedup vs baseline: 1.1802x; 1.1802x over previous
//
#include <hip/hip_runtime.h>
#include <hip/hip_bf16.h>
#include <cstdio>

#define HID 256

using short8  = __attribute__((ext_vector_type(8))) short;
using floatx4 = __attribute__((ext_vector_type(4))) float;
using uintx8  = __attribute__((ext_vector_type(8))) unsigned int;

__device__ inline unsigned short bf16_rn(float x) {
    unsigned u = __float_as_uint(x);
    return (unsigned short)((u + 0x7FFFu + ((u >> 16) & 1u)) >> 16);
}
__device__ inline float bf2f(unsigned short u) {
    return __uint_as_float(((unsigned)u) << 16);
}
// packed uint32 = (hi_bf16 << 16) | lo_bf16
__device__ inline unsigned pack_hl(float v) {
    unsigned short h = bf16_rn(v);
    unsigned short lo = bf16_rn(v - bf2f(h));
    return ((unsigned)h << 16) | (unsigned)lo;
}
__device__ inline float unpack_sum(unsigned u) {
    return __uint_as_float(u & 0xFFFF0000u) + __uint_as_float(u << 16);
}
// uintx8 (8 packed elems) -> hi short8 + lo short8
__device__ inline void unpack8(uintx8 u, short8& h, short8& l) {
    union { unsigned w[4]; short8 s; } H, L;
#pragma unroll
    for (int i = 0; i < 4; i++) {
        unsigned a = u[2 * i], b = u[2 * i + 1];
        H.w[i] = (a >> 16) | (b & 0xFFFF0000u);
        L.w[i] = (a & 0x0000FFFFu) | (b << 16);
    }
    h = H.s; l = L.s;
}

// ---------------- diagnostic marker (ws too small) ----------------
__global__ void marker_k(float* __restrict__ out, int n, float v) {
    int i = blockIdx.x * blockDim.x + threadIdx.x;
    if (i < n) out[i] = v;
}

// ---------------- int64-vs-int32 detection ----------------
__global__ void detect64_k(const unsigned* __restrict__ eiw, int E,
                           const unsigned* __restrict__ bw, int Nh,
                           int* __restrict__ any_nonzero) {
    int total = E + Nh;
    unsigned loc = 0;
    for (int i = blockIdx.x * blockDim.x + threadIdx.x; i < total;
         i += gridDim.x * blockDim.x) {
        loc |= (i < E) ? eiw[2 * i + 1] : bw[2 * (i - E) + 1];
    }
    if (loc) atomicOr(any_nonzero, 1);
}

__global__ void norm_idx_k(const int* __restrict__ src, int* __restrict__ dst,
                           int n, const int* __restrict__ any_nonzero) {
    int is64 = (any_nonzero[0] == 0);
    for (int i = blockIdx.x * blockDim.x + threadIdx.x; i < n;
         i += gridDim.x * blockDim.x) {
        dst[i] = is64 ? src[2 * i] : src[i];
    }
}

// ---------------- graph boundaries (batch is sorted) ----------------
__global__ void pool_bounds_k(const int* __restrict__ batch, int N, int G,
                              int* __restrict__ starts) {
    int g = blockIdx.x * blockDim.x + threadIdx.x;
    if (g > G) return;
    int lo = 0, hi = N;
    while (lo < hi) {
        int mid = (lo + hi) >> 1;
        if (batch[mid] < g) lo = mid + 1; else hi = mid;
    }
    starts[g] = lo;
}

// ---------------- CSR build ----------------
__global__ void deg_count_k(const int* __restrict__ ei, int E, int N,
                            int* __restrict__ deg) {
    int e = blockIdx.x * blockDim.x + threadIdx.x;
    if (e >= E) return;
    int s = ei[e];
    int d = ei[E + e];
    if ((unsigned)s >= (unsigned)N || (unsigned)d >= (unsigned)N) return;
    atomicAdd(&deg[d], 1);
}

#define SCAN_BLK 256

__global__ __launch_bounds__(SCAN_BLK) void scan_a_k(const int* __restrict__ deg,
                                                     int* __restrict__ bsum, int N) {
    __shared__ int red[SCAN_BLK];
    int i = blockIdx.x * SCAN_BLK + threadIdx.x;
    int v = (i < N) ? deg[i] : 0;
    red[threadIdx.x] = v;
    __syncthreads();
#pragma unroll
    for (int off = SCAN_BLK / 2; off > 0; off >>= 1) {
        if (threadIdx.x < off) red[threadIdx.x] += red[threadIdx.x + off];
        __syncthreads();
    }
    if (threadIdx.x == 0) bsum[blockIdx.x] = red[0];
}

__global__ __launch_bounds__(1024) void scan_b_k(int* __restrict__ bsum, int nb) {
    __shared__ int tsum[1024];
    int t = threadIdx.x;
    int v = (t < nb) ? bsum[t] : 0;
    tsum[t] = v;
    __syncthreads();
    for (int off = 1; off < 1024; off <<= 1) {
        int u = (t >= off) ? tsum[t - off] : 0;
        __syncthreads();
        tsum[t] += u;
        __syncthreads();
    }
    if (t < nb) bsum[t] = tsum[t] - v;
}

__global__ __launch_bounds__(SCAN_BLK) void scan_c_k(const int* __restrict__ deg,
                                                     const int* __restrict__ bsum,
                                                     int* __restrict__ row_ptr, int N) {
    __shared__ int tsum[SCAN_BLK];
    int t = threadIdx.x;
    int i = blockIdx.x * SCAN_BLK + t;
    int v = (i < N) ? deg[i] : 0;
    tsum[t] = v;
    __syncthreads();
    for (int off = 1; off < SCAN_BLK; off <<= 1) {
        int u = (t >= off) ? tsum[t - off] : 0;
        __syncthreads();
        tsum[t] += u;
        __syncthreads();
    }
    if (i <= N) row_ptr[i] = tsum[t] - v + bsum[blockIdx.x];
}

__global__ __launch_bounds__(1024) void scan_rowptr_k(const int* __restrict__ deg,
                                                      int* __restrict__ row_ptr, int N) {
    __shared__ int tsum[1024];
    int t = threadIdx.x;
    int chunk = (N + 1023) / 1024;
    int lo = t * chunk;
    int hi = min(lo + chunk, N);
    int s = 0;
    for (int i = lo; i < hi; i++) s += deg[i];
    tsum[t] = s;
    __syncthreads();
    for (int off = 1; off < 1024; off <<= 1) {
        int v = (t >= off) ? tsum[t - off] : 0;
        __syncthreads();
        tsum[t] += v;
        __syncthreads();
    }
    int run = (t == 0) ? 0 : tsum[t - 1];
    for (int i = lo; i < hi; i++) { row_ptr[i] = run; run += deg[i]; }
    if (hi >= N && lo <= N) row_ptr[N] = run;
}

__global__ void fill_csr_k(const int* __restrict__ ei, int E, int N,
                           const int* __restrict__ row_ptr, int* __restrict__ cursor,
                           int* __restrict__ esrc) {
    int e = blockIdx.x * blockDim.x + threadIdx.x;
    if (e >= E) return;
    int s = ei[e];
    int d = ei[E + e];
    if ((unsigned)s >= (unsigned)N || (unsigned)d >= (unsigned)N) return;
    int pos = atomicAdd(&cursor[d], 1);
    esrc[row_ptr[d] + pos] = s;
}

// ---------------- gather aggregation, 28-wide (layer 1, fp32) ----------------
__global__ void gather28_k(const float* __restrict__ x, const int* __restrict__ row_ptr,
                           const int* __restrict__ esrc, float* __restrict__ Q28, int N) {
    int gid = blockIdx.x * blockDim.x + threadIdx.x;
    int node = gid >> 5;
    if (node >= N) return;
    int lane = gid & 31;
    if (lane >= 28) return;
    int s = row_ptr[node], e = row_ptr[node + 1];
    float acc = 0.f;
    for (int i = s; i < e; i++) {
        int src = esrc[i];
        acc += x[(size_t)src * 28 + lane];
    }
    Q28[(size_t)node * 28 + lane] = acc;
}

// ---------------- gather: Pp(packed) -> Qp(packed) ----------------
__global__ void gather256p_k(const unsigned* __restrict__ Pp,
                             const int* __restrict__ row_ptr,
                             const int* __restrict__ esrc,
                             unsigned* __restrict__ Qp, int N) {
    int gid = blockIdx.x * blockDim.x + threadIdx.x;
    int node = gid >> 6;
    if (node >= N) return;
    int lane = gid & 63;
    int s = row_ptr[node], e = row_ptr[node + 1];
    float a0 = 0.f, a1 = 0.f, a2 = 0.f, a3 = 0.f;
    for (int i = s; i < e; i++) {
        int src = esrc[i];
        uint4 u = *(const uint4*)(Pp + (size_t)src * HID + lane * 4);
        a0 += unpack_sum(u.x);
        a1 += unpack_sum(u.y);
        a2 += unpack_sum(u.z);
        a3 += unpack_sum(u.w);
    }
    uint4 o;
    o.x = pack_hl(a0); o.y = pack_hl(a1); o.z = pack_hl(a2); o.w = pack_hl(a3);
    *(uint4*)(Qp + (size_t)node * HID + lane * 4) = o;
}

// ---------------- layer 1 fused -> Pp (packed) ----------------
__global__ __launch_bounds__(256) void l1_fused_k(
    const float* __restrict__ x, const float* __restrict__ agg,
    const float* __restrict__ Wrel, const float* __restrict__ Wroot,
    const float* __restrict__ bias, unsigned* __restrict__ Pp, int M) {
    __shared__ float As[64][28];
    __shared__ float Xs[64][28];
    int t = threadIdx.x;
    int n0 = blockIdx.x * 64;
    float wrel[28], wroot[28];
#pragma unroll
    for (int k = 0; k < 28; k++) {
        wrel[k]  = Wrel[t * 28 + k];
        wroot[k] = Wroot[t * 28 + k];
    }
    float b = bias[t];
    for (int idx = t; idx < 64 * 28; idx += 256) {
        int r = idx / 28;
        int c = idx - r * 28;
        int gr = n0 + r;
        As[r][c] = (gr < M) ? agg[(size_t)gr * 28 + c] : 0.f;
        Xs[r][c] = (gr < M) ? x[(size_t)gr * 28 + c] : 0.f;
    }
    __syncthreads();
    int nmax = min(64, M - n0);
    for (int n = 0; n < nmax; n++) {
        float acc = b;
#pragma unroll
        for (int k4 = 0; k4 < 28; k4 += 4) {
            float4 a  = *(const float4*)&As[n][k4];
            float4 xx = *(const float4*)&Xs[n][k4];
            acc += a.x * wrel[k4] + a.y * wrel[k4 + 1] + a.z * wrel[k4 + 2] + a.w * wrel[k4 + 3];
            acc += xx.x * wroot[k4] + xx.y * wroot[k4 + 1] + xx.z * wroot[k4 + 2] + xx.w * wroot[k4 + 3];
        }
        Pp[(size_t)(n0 + n) * HID + t] = pack_hl(fmaxf(acc, 0.f));
    }
}

// ---------------- weight split: 6 matrices fp32 -> (hi, lo) bf16 planes ----------------
__global__ void wsplit6_k(const float* W0, const float* W1, const float* W2,
                          const float* W3, const float* W4, const float* W5,
                          unsigned short* __restrict__ out_hl, int n) {
    int i = blockIdx.x * blockDim.x + threadIdx.x;
    if (i >= n) return;
    const float* W = (blockIdx.y == 0) ? W0 : (blockIdx.y == 1) ? W1 :
                     (blockIdx.y == 2) ? W2 : (blockIdx.y == 3) ? W3 :
                     (blockIdx.y == 4) ? W4 : W5;
    unsigned short* o = out_hl + (size_t)blockIdx.y * 2 * n;
    float a = W[i];
    unsigned short h = bf16_rn(a);
    o[i] = h;
    o[n + i] = bf16_rn(a - bf2f(h));
}

// ---------------- MFMA strip GEMM (round-7 structure, packed activations) ----------------
// Pp[strip] = relu(Qp@Wr.T + Pp@Wo.T + bias). 64-row strip, 256 thr, 4 waves;
// wave w owns cols [w*64, w*64+64). A: packed uint, unpacked at staging.
// W: pre-split hi/lo ushort planes, staged by pure copy. In-place safe.
#define LSTR 40

__global__ __launch_bounds__(256) void gemm_strip_mfma_k(
    const unsigned* __restrict__ Qp, const unsigned short* __restrict__ Wr_hl,
    unsigned* __restrict__ Pp, const unsigned short* __restrict__ Wo_hl,
    const float* __restrict__ bias, int M) {
    __shared__ unsigned short Ah[64 * LSTR], Al[64 * LSTR];     // 5 KB each
    __shared__ unsigned short Wh[256 * LSTR], Wl[256 * LSTR];   // 20 KB each
    int t = threadIdx.x;
    int brow = blockIdx.x * 64;
    int w = t >> 6;
    int l = t & 63;

    floatx4 acc[4][4];
#pragma unroll
    for (int i = 0; i < 4; i++)
#pragma unroll
        for (int j = 0; j < 4; j++) acc[i][j] = (floatx4){0.f, 0.f, 0.f, 0.f};

    int srow = t >> 2;       // 0..63
    int sg   = t & 3;        // k-granule of 8

    for (int ch = 0; ch < 16; ch++) {
        int phase2 = (ch >= 8);
        const unsigned* A = phase2 ? Pp : Qp;
        const unsigned short* Whl = phase2 ? Wo_hl : Wr_hl;
        int kbase = (ch & 7) * 32;

        // ---- stage A: 64 rows x 32 k, one 32B packed load + unpack ----
        {
            int gr = brow + srow;
            short8 hv = {}, lv = {};
            if (gr < M) {
                uintx8 u = *(const uintx8*)(A + (size_t)gr * HID + kbase + sg * 8);
                unpack8(u, hv, lv);
            }
            int base = srow * LSTR + sg * 8;
            *(short8*)(Ah + base) = hv;
            *(short8*)(Al + base) = lv;
        }
        // ---- stage W: 256 cols x 32 k (4 cols per thread), pure copy ----
#pragma unroll
        for (int i = 0; i < 4; i++) {
            int col = srow + i * 64;
            short8 hh = *(const short8*)(Whl + (size_t)col * HID + kbase + sg * 8);
            short8 ll = *(const short8*)(Whl + 65536 + (size_t)col * HID + kbase + sg * 8);
            int base = col * LSTR + sg * 8;
            *(short8*)(Wh + base) = hh;
            *(short8*)(Wl + base) = ll;
        }
        __syncthreads();

        int frow = l & 15;
        int fg   = l >> 4;
        short8 ahf[4], alf[4], whf[4], wlf[4];
#pragma unroll
        for (int rt = 0; rt < 4; rt++) {
            int base = (rt * 16 + frow) * LSTR + fg * 8;
            ahf[rt] = *(short8*)(Ah + base);
            alf[rt] = *(short8*)(Al + base);
        }
#pragma unroll
        for (int ct = 0; ct < 4; ct++) {
            int base = (w * 64 + ct * 16 + frow) * LSTR + fg * 8;
            whf[ct] = *(short8*)(Wh + base);
            wlf[ct] = *(short8*)(Wl + base);
        }
#pragma unroll
        for (int rt = 0; rt < 4; rt++)
#pragma unroll
            for (int ct = 0; ct < 4; ct++) {
                acc[rt][ct] = __builtin_amdgcn_mfma_f32_16x16x32_bf16(
                    ahf[rt], whf[ct], acc[rt][ct], 0, 0, 0);
                acc[rt][ct] = __builtin_amdgcn_mfma_f32_16x16x32_bf16(
                    alf[rt], whf[ct], acc[rt][ct], 0, 0, 0);
                acc[rt][ct] = __builtin_amdgcn_mfma_f32_16x16x32_bf16(
                    ahf[rt], wlf[ct], acc[rt][ct], 0, 0, 0);
            }
        __syncthreads();
    }

    // ---- epilogue: relu(acc+bias) -> packed uint, coalesced 4B stores ----
#pragma unroll
    for (int ct = 0; ct < 4; ct++) {
        int gc = w * 64 + ct * 16 + (l & 15);
        float bs = bias[gc];
#pragma unroll
        for (int rt = 0; rt < 4; rt++) {
            floatx4 a = acc[rt][ct];
#pragma unroll
            for (int r = 0; r < 4; r++) {
                int gr = brow + rt * 16 + (l >> 4) * 4 + r;
                if (gr < M)
                    Pp[(size_t)gr * HID + gc] = pack_hl(fmaxf(a[r] + bs, 0.f));
            }
        }
    }
}

// ---------------- per-layer mean-pool slice (packed input) ----------------
__global__ __launch_bounds__(256) void pool_slice_k(const unsigned* __restrict__ Pp,
                                                    const int* __restrict__ starts,
                                                    float* __restrict__ gslice, int N) {
    int g = blockIdx.x;
    int t = threadIdx.x;
    int s = starts[g], e = starts[g + 1];
    s = max(0, min(s, N));
    e = max(s, min(e, N));
    float a = 0.f;
    for (int n = s; n < e; n++) a += unpack_sum(Pp[(size_t)n * HID + t]);
    float inv = 1.f / (float)max(e - s, 1);
    gslice[(size_t)g * 1024 + t] = a * inv;
}

// ---------------- out-of-place dual GEMM (MLP head, fp32) ----------------
#define BM 64
#define BN 64
#define BK 32
#define LP 68

__global__ __launch_bounds__(256) void gemm_dual_k(
    const float* __restrict__ A1, int lda1, const float* __restrict__ W1,
    const float* __restrict__ A2, int lda2, const float* __restrict__ W2,
    const float* __restrict__ bias, float* __restrict__ out, int ldout,
    int M, int K1, int K2, int relu) {
    __shared__ float As[BK][LP];
    __shared__ float Ws[BK][LP];
    int t = threadIdx.x;
    int brow = blockIdx.x * BM;
    int bcol = blockIdx.y * BN;
    int tx = t & 15, ty = t >> 4;
    float acc[4][4] = {{0.f}};
    int Ktot = K1 + K2;
    int srow = t >> 3;
    int sk4 = (t & 7) << 2;

    for (int kk = 0; kk < Ktot; kk += BK) {
        int phase2 = (kk >= K1);
        const float* A = phase2 ? A2 : A1;
        const float* W = phase2 ? W2 : W1;
        int lda = phase2 ? lda2 : lda1;
        int ldw = phase2 ? K2 : K1;
        int kbase = phase2 ? (kk - K1) : kk;
#pragma unroll
        for (int i = 0; i < 2; i++) {
            int r = srow + i * 32;
            int gr = brow + r;
            float4 v = make_float4(0.f, 0.f, 0.f, 0.f);
            if (gr < M) v = *(const float4*)(A + (size_t)gr * lda + kbase + sk4);
            As[sk4 + 0][r] = v.x; As[sk4 + 1][r] = v.y;
            As[sk4 + 2][r] = v.z; As[sk4 + 3][r] = v.w;
            float4 w = *(const float4*)(W + (size_t)(bcol + r) * ldw + kbase + sk4);
            Ws[sk4 + 0][r] = w.x; Ws[sk4 + 1][r] = w.y;
            Ws[sk4 + 2][r] = w.z; Ws[sk4 + 3][r] = w.w;
        }
        __syncthreads();
#pragma unroll
        for (int k = 0; k < BK; k++) {
            float4 a = *(const float4*)&As[k][ty << 2];
            float4 w = *(const float4*)&Ws[k][tx << 2];
            float av[4] = {a.x, a.y, a.z, a.w};
            float wv[4] = {w.x, w.y, w.z, w.w};
#pragma unroll
            for (int i = 0; i < 4; i++)
#pragma unroll
                for (int j = 0; j < 4; j++)
                    acc[i][j] = fmaf(av[i], wv[j], acc[i][j]);
        }
        __syncthreads();
    }
#pragma unroll
    for (int i = 0; i < 4; i++) {
        int gr = brow + (ty << 2) + i;
        if (gr >= M) continue;
#pragma unroll
        for (int j = 0; j < 4; j++) {
            int gc = bcol + (tx << 2) + j;
            float v = acc[i][j] + bias[gc];
            if (relu) v = fmaxf(v, 0.f);
            out[(size_t)gr * ldout + gc] = v;
        }
    }
}

// ---------------- fc4 ----------------
__global__ void fc4_k(const float* __restrict__ in, const float* __restrict__ w,
                      const float* __restrict__ b, float* __restrict__ out, int M) {
    int gid = blockIdx.x * blockDim.x + threadIdx.x;
    int row = gid >> 6;
    if (row >= M) return;
    int lane = gid & 63;
    float4 v  = *(const float4*)(in + (size_t)row * HID + lane * 4);
    float4 ww = *(const float4*)(w + lane * 4);
    float acc = v.x * ww.x + v.y * ww.y + v.z * ww.z + v.w * ww.w;
#pragma unroll
    for (int off = 32; off; off >>= 1) acc += __shfl_down(acc, off);
    if (lane == 0) out[row] = acc + b[0];
}

extern "C" void kernel_launch(void* const* d_in, const int* in_sizes, int n_in,
                              void* d_out, int out_size, void* d_ws, size_t ws_size,
                              hipStream_t stream) {
    const int N = in_sizes[0] / 28;       // 100000
    const int E = in_sizes[1] / 2;        // 320000
    const int G = out_size;               // 4096

    const float* x        = (const float*)d_in[0];
    const int*   ei_raw   = (const int*)d_in[1];
    const int*   b_raw    = (const int*)d_in[2];
    const float* W1_rel  = (const float*)d_in[3];
    const float* b1      = (const float*)d_in[4];
    const float* W1_root = (const float*)d_in[5];
    const float* W2_rel  = (const float*)d_in[6];
    const float* b2      = (const float*)d_in[7];
    const float* W2_root = (const float*)d_in[8];
    const float* W3_rel  = (const float*)d_in[9];
    const float* b3      = (const float*)d_in[10];
    const float* W3_root = (const float*)d_in[11];
    const float* W4_rel  = (const float*)d_in[12];
    const float* b4      = (const float*)d_in[13];
    const float* W4_root = (const float*)d_in[14];
    const float* fc1_w = (const float*)d_in[15];
    const float* fc1_b = (const float*)d_in[16];
    const float* fc2_w = (const float*)d_in[17];
    const float* fc2_b = (const float*)d_in[18];
    const float* fc3_w = (const float*)d_in[19];
    const float* fc3_b = (const float*)d_in[20];
    const float* fc4_w = (const float*)d_in[21];
    const float* fc4_b = (const float*)d_in[22];
    float* out = (float*)d_out;

    // ---- workspace layout (float units). Pp/Qp = N*HID packed uints ----
    size_t fN  = (size_t)N * HID;
    size_t off_P      = 0;
    size_t off_Q      = off_P + fN;     // fp32 Q28 prefix for layer 1, packed later
    size_t off_gpool  = off_Q + fN;
    size_t off_t1     = off_gpool + (size_t)G * 1024;
    size_t off_t2     = off_t1 + (size_t)G * HID;
    size_t off_ei     = off_t2 + (size_t)G * HID;
    size_t off_batch  = off_ei + (size_t)2 * E;
    size_t off_starts = off_batch + (size_t)N;
    size_t off_flag   = off_starts + (size_t)(G + 1);
    size_t off_deg    = off_flag + 1;
    size_t off_cur    = off_deg + (size_t)N;
    size_t off_rowp   = off_cur + (size_t)N;
    size_t off_bsum   = off_rowp + (size_t)(N + 1);
    size_t off_esrc   = off_bsum + 1024;
    size_t off_wsplit = (off_esrc + (size_t)E + 7) & ~(size_t)7;  // 32B-align
    size_t need = (off_wsplit + 393216 + 16) * 4;   // 6 matrices x 2x65536 ushorts

    if (ws_size < need) {
        fprintf(stderr, "[kernel_launch] ws too small: ws=%zu need=%zu\n", ws_size, need);
        marker_k<<<(G + 255) / 256, 256, 0, stream>>>(out, G, (float)(ws_size >> 20));
        return;
    }

    float* wsf   = (float*)d_ws;
    unsigned* Pp = (unsigned*)(wsf + off_P);
    float* Q     = wsf + off_Q;
    unsigned* Qp = (unsigned*)Q;
    float* gpool = wsf + off_gpool;
    float* t1    = wsf + off_t1;
    float* t2    = wsf + off_t2;
    int* nei     = (int*)(wsf + off_ei);
    int* nbatch  = (int*)(wsf + off_batch);
    int* starts  = (int*)(wsf + off_starts);
    int* flag    = (int*)(wsf + off_flag);
    int* deg     = (int*)(wsf + off_deg);
    int* cursor  = (int*)(wsf + off_cur);
    int* row_ptr = (int*)(wsf + off_rowp);
    int* bsum    = (int*)(wsf + off_bsum);
    int* esrc    = (int*)(wsf + off_esrc);
    unsigned short* wsplit = (unsigned short*)(wsf + off_wsplit);

    // ---- normalize index dtype (int64 vs int32) on-device ----
    hipMemsetAsync(flag, 0, sizeof(int), stream);
    detect64_k<<<1024, 256, 0, stream>>>((const unsigned*)ei_raw, E,
                                         (const unsigned*)b_raw, N / 2, flag);
    norm_idx_k<<<1024, 256, 0, stream>>>(ei_raw, nei, 2 * E, flag);
    norm_idx_k<<<512, 256, 0, stream>>>(b_raw, nbatch, N, flag);

    pool_bounds_k<<<(G + 1 + 255) / 256, 256, 0, stream>>>(nbatch, N, G, starts);

    // ---- build CSR by destination ----
    hipMemsetAsync(deg, 0, 2 * (size_t)N * sizeof(int), stream);
    deg_count_k<<<(E + 255) / 256, 256, 0, stream>>>(nei, E, N, deg);
    int nb = (N + 1 + SCAN_BLK - 1) / SCAN_BLK;
    if (nb <= 1024) {
        scan_a_k<<<nb, SCAN_BLK, 0, stream>>>(deg, bsum, N);
        scan_b_k<<<1, 1024, 0, stream>>>(bsum, nb);
        scan_c_k<<<nb, SCAN_BLK, 0, stream>>>(deg, bsum, row_ptr, N);
    } else {
        scan_rowptr_k<<<1, 1024, 0, stream>>>(deg, row_ptr, N);
    }
    fill_csr_k<<<(E + 255) / 256, 256, 0, stream>>>(nei, E, N, row_ptr, cursor, esrc);

    // ---- pre-split GraphConv weights to hi/lo planes ----
    wsplit6_k<<<dim3((65536 + 255) / 256, 6), 256, 0, stream>>>(
        W2_rel, W2_root, W3_rel, W3_root, W4_rel, W4_root, wsplit, 65536);

    // ---- layer 1: gather 28-wide (fp32) into Q, fused GEMM -> Pp (packed) ----
    gather28_k<<<((size_t)N * 32 + 255) / 256, 256, 0, stream>>>(x, row_ptr, esrc, Q, N);
    l1_fused_k<<<(N + 63) / 64, 256, 0, stream>>>(x, Q, W1_rel, W1_root, b1, Pp, N);
    pool_slice_k<<<G, 256, 0, stream>>>(Pp, starts, gpool + 0, N);

    // ---- layers 2..4: gather Pp -> Qp; LDS-MFMA GEMM in-place on Pp; pool ----
    int nstrips = (N + 63) / 64;
    const float* bb[3] = {b2, b3, b4};
    for (int l = 0; l < 3; l++) {
        gather256p_k<<<((size_t)N * 64 + 255) / 256, 256, 0, stream>>>(Pp, row_ptr, esrc, Qp, N);
        gemm_strip_mfma_k<<<nstrips, 256, 0, stream>>>(
            Qp, wsplit + (size_t)(2 * l) * 131072,
            Pp, wsplit + (size_t)(2 * l + 1) * 131072, bb[l], N);
        pool_slice_k<<<G, 256, 0, stream>>>(Pp, starts, gpool + 256 * (l + 1), N);
    }

    // ---- MLP head ----
    dim3 gdimG(G / BM, HID / BN);
    gemm_dual_k<<<gdimG, 256, 0, stream>>>(gpool, 1024, fc1_w, nullptr, 0, nullptr,
                                           fc1_b, t1, HID, G, 1024, 0, 1);
    gemm_dual_k<<<gdimG, 256, 0, stream>>>(t1, HID, fc2_w, nullptr, 0, nullptr,
                                           fc2_b, t2, HID, G, HID, 0, 1);
    gemm_dual_k<<<gdimG, 256, 0, stream>>>(t2, HID, fc3_w, nullptr, 0, nullptr,
                                           fc3_b, t1, HID, G, HID, 0, 1);
    fc4_k<<<(G * 64 + 255) / 256, 256, 0, stream>>>(t1, fc4_w, fc4_b, out, G);
}